// Round 9
// baseline (145.853 us; speedup 1.0000x reference)
//
#include <hip/hip_runtime.h>

// Problem constants
constexpr int kB  = 2;
constexpr int kL  = 8192;   // d*h*w = 8*32*32
constexpr int kC  = 128;    // D_MODEL
constexpr int kE  = 256;    // D_INNER
constexpr int kN  = 16;     // D_STATE
constexpr int kCL = 64;     // scan chunk length
constexpr int kNC = kL / kCL; // 128 chunks per batch

typedef __attribute__((ext_vector_type(8))) short bf16x8;
typedef __attribute__((ext_vector_type(4))) float f32x4;
typedef __attribute__((ext_vector_type(8))) unsigned short u16x8;

__device__ __forceinline__ float silu(float v) { return v / (1.f + __expf(-v)); }
__device__ __forceinline__ float softplusf(float s) {
  return fmaxf(s, 0.f) + log1pf(__expf(-fabsf(s)));
}
__device__ __forceinline__ unsigned short f2bf(float x) {
  unsigned u = __float_as_uint(x);
  u += 0x7FFF + ((u >> 16) & 1);
  return (unsigned short)(u >> 16);
}
__device__ __forceinline__ float bf2f(unsigned short x) {
  return __uint_as_float(((unsigned)x) << 16);
}
// Sum over aligned 8-lane groups entirely on the VALU pipe (DPP), no DS ops.
__device__ __forceinline__ float dpp_red8(float v) {
  v += __int_as_float(__builtin_amdgcn_mov_dpp(__float_as_int(v), 0xB1, 0xF, 0xF, true));
  v += __int_as_float(__builtin_amdgcn_mov_dpp(__float_as_int(v), 0x4E, 0xF, 0xF, true));
  v += __int_as_float(__builtin_amdgcn_mov_dpp(__float_as_int(v), 0x141, 0xF, 0xF, true));
  return v;
}

// ---------------------------------------------------------------------------
// Kernel: fused weight-prep (blocks 0..83) + LayerNorm (blocks 84..339).
// ---------------------------------------------------------------------------
__global__ __launch_bounds__(256) void k_pre(const float* __restrict__ W_in,
                                             const float* __restrict__ W_x,
                                             const float* __restrict__ W_dt,
                                             const float* __restrict__ W_out,
                                             unsigned short* __restrict__ WinF,
                                             unsigned short* __restrict__ WcatF,
                                             unsigned short* __restrict__ WoutF,
                                             const float* __restrict__ x,
                                             const float* __restrict__ ln_w,
                                             const float* __restrict__ ln_b,
                                             unsigned short* __restrict__ xnH) {
  const int tid = threadIdx.x;
  if (blockIdx.x < 84) {
    const int f = blockIdx.x * 256 + tid;
    u16x8 o;
    if (f < 8192) {
      const int lane = f & 63, ks = (f >> 6) & 3, mt = f >> 8;
      const int m = mt * 16 + (lane & 15), kb = ks * 32 + ((lane >> 4) << 3);
      #pragma unroll
      for (int j = 0; j < 8; ++j) o[j] = f2bf(W_in[m * 128 + kb + j]);
      *(u16x8*)&WinF[(size_t)f * 8] = o;
    } else if (f < 17408) {
      const int g = f - 8192;
      const int lane = g & 63, ks = (g >> 6) & 7, mt = g >> 9;
      const int m = mt * 16 + (lane & 15), kb = ks * 32 + ((lane >> 4) << 3);
      if (m < 256) {
        #pragma unroll
        for (int j = 0; j < 8; ++j) {
          float s = 0.f;
          #pragma unroll
          for (int r = 0; r < 8; ++r) s = fmaf(W_dt[m * 8 + r], W_x[r * 256 + kb + j], s);
          o[j] = f2bf(s);
        }
      } else {
        #pragma unroll
        for (int j = 0; j < 8; ++j) o[j] = f2bf(W_x[(8 + m - 256) * 256 + kb + j]);
      }
      *(u16x8*)&WcatF[(size_t)g * 8] = o;
    } else {
      const int g = f - 17408;
      const int lane = g & 63, ks = (g >> 6) & 7, mt = g >> 9;
      const int m = mt * 16 + (lane & 15), kb = ks * 32 + ((lane >> 4) << 3);
      #pragma unroll
      for (int j = 0; j < 8; ++j) o[j] = f2bf(W_out[m * 256 + kb + j]);
      *(u16x8*)&WoutF[(size_t)g * 8] = o;
    }
    return;
  }
  // ---- LayerNorm part ----
  __shared__ float tile[64 * 132];
  __shared__ float smu[64], srs[64];
  const int bx2 = blockIdx.x - 84;
  const int b = bx2 >> 7, l0 = (bx2 & 127) * 64;
  const int cc = tid >> 6, lt = tid & 63;
  const float* xb = x + (size_t)b * kC * kL;
  for (int c0 = 0; c0 < kC; c0 += 4)
    tile[lt * 132 + c0 + cc] = xb[(size_t)(c0 + cc) * kL + l0 + lt];
  __syncthreads();
  const int l = tid >> 2, q = tid & 3;
  float s = 0.f, s2 = 0.f;
  #pragma unroll
  for (int i = 0; i < 32; ++i) {
    const float v = tile[l * 132 + q + 4 * i];
    s += v; s2 += v * v;
  }
  s += __shfl_xor(s, 1);  s2 += __shfl_xor(s2, 1);
  s += __shfl_xor(s, 2);  s2 += __shfl_xor(s2, 2);
  if (q == 0) {
    const float mu = s * (1.f / 128.f);
    const float var = s2 * (1.f / 128.f) - mu * mu;
    smu[l] = mu; srs[l] = rsqrtf(var + 1e-5f);
  }
  __syncthreads();
  #pragma unroll
  for (int it = 0; it < 4; ++it) {
    const int fidx = tid + it * 256;
    const int li = fidx >> 4, c8 = fidx & 15;
    const float4 v0 = *(const float4*)&tile[li * 132 + c8 * 8];
    const float4 v1 = *(const float4*)&tile[li * 132 + c8 * 8 + 4];
    const float4 w0 = *(const float4*)&ln_w[c8 * 8];
    const float4 w1 = *(const float4*)&ln_w[c8 * 8 + 4];
    const float4 b0 = *(const float4*)&ln_b[c8 * 8];
    const float4 b1 = *(const float4*)&ln_b[c8 * 8 + 4];
    const float mu = smu[li], rs = srs[li];
    u16x8 o;
    o[0] = f2bf((v0.x - mu) * rs * w0.x + b0.x);
    o[1] = f2bf((v0.y - mu) * rs * w0.y + b0.y);
    o[2] = f2bf((v0.z - mu) * rs * w0.z + b0.z);
    o[3] = f2bf((v0.w - mu) * rs * w0.w + b0.w);
    o[4] = f2bf((v1.x - mu) * rs * w1.x + b1.x);
    o[5] = f2bf((v1.y - mu) * rs * w1.y + b1.y);
    o[6] = f2bf((v1.z - mu) * rs * w1.z + b1.z);
    o[7] = f2bf((v1.w - mu) * rs * w1.w + b1.w);
    *(u16x8*)&xnH[((size_t)b * kL + l0 + li) * kC + c8 * 8] = o;
  }
}

// ---------------------------------------------------------------------------
// Kernel: fused GEMM1 + depthwise conv + silu.
// ct 0..1: xi slices -> conv -> xcC bf16 ch-major + xcH bf16 token-major
// ct 2..3: z slices  -> LDS transpose -> zH bf16 ch-major (coalesced)
// ---------------------------------------------------------------------------
__global__ __launch_bounds__(256) void k_g1conv(const unsigned short* __restrict__ xnH,
                                                const unsigned short* __restrict__ WF,
                                                const float* __restrict__ W_in,
                                                const float* __restrict__ conv_w,
                                                const float* __restrict__ conv_b,
                                                unsigned short* __restrict__ zH,
                                                unsigned short* __restrict__ xcC,
                                                unsigned short* __restrict__ xcH) {
  constexpr int KPAD = 136;
  __shared__ unsigned short Xs[64 * KPAD];   // staging; aliased as ht[64*72] later
  __shared__ float xi[128 * 69];             // conv tile; aliased as ht2 u16[128*72] (z path)
  const int b = blockIdx.z, ct = blockIdx.y, l0 = blockIdx.x * 64;
  const int tid = threadIdx.x, lane = tid & 63, w = tid >> 6;
  for (int si = tid; si < 1024; si += 256) {
    const int l = si >> 4, k8 = si & 15;
    *(uint4*)&Xs[l * KPAD + k8 * 8] =
        *(const uint4*)&xnH[((size_t)(b * kL + l0 + l)) * kC + k8 * 8];
  }
  __syncthreads();
  // boundary-token xi via VALU (xi slices only); zeros when l0 == 0
  float s0 = 0.f, s1 = 0.f, s2 = 0.f;
  if (ct < 2 && tid < 128 && l0 > 0) {
    const int ge = ct * 128 + tid;
    const float4* wv = (const float4*)&W_in[ge * kC];
    const u16x8* x0 = (const u16x8*)&xnH[((size_t)b * kL + l0 - 3) * kC];
    const u16x8* x1 = (const u16x8*)&xnH[((size_t)b * kL + l0 - 2) * kC];
    const u16x8* x2 = (const u16x8*)&xnH[((size_t)b * kL + l0 - 1) * kC];
    #pragma unroll 4
    for (int k8 = 0; k8 < 16; ++k8) {
      const float4 wa = wv[2 * k8], wb = wv[2 * k8 + 1];
      const u16x8 a0 = x0[k8], a1 = x1[k8], a2 = x2[k8];
      const float wreg[8] = {wa.x, wa.y, wa.z, wa.w, wb.x, wb.y, wb.z, wb.w};
      #pragma unroll
      for (int j = 0; j < 8; ++j) {
        s0 = fmaf(wreg[j], bf2f(a0[j]), s0);
        s1 = fmaf(wreg[j], bf2f(a1[j]), s1);
        s2 = fmaf(wreg[j], bf2f(a2[j]), s2);
      }
    }
  }
  if (ct < 2 && tid < 128) {
    xi[tid * 69 + 0] = s0; xi[tid * 69 + 1] = s1; xi[tid * 69 + 2] = s2;
  }
  // MFMA: 128 rows of this ct-slice; waves do mt = w, w+4
  f32x4 acc[2][4];
  #pragma unroll
  for (int i = 0; i < 2; ++i)
    #pragma unroll
    for (int lt = 0; lt < 4; ++lt) acc[i][lt] = (f32x4){0.f, 0.f, 0.f, 0.f};
  const int colo = lane & 15, kgrp = (lane >> 4) * 8;
  for (int ks = 0; ks < 4; ++ks) {
    bf16x8 Bf[4];
    #pragma unroll
    for (int lt = 0; lt < 4; ++lt)
      Bf[lt] = *(const bf16x8*)&Xs[(lt * 16 + colo) * KPAD + ks * 32 + kgrp];
    #pragma unroll
    for (int i = 0; i < 2; ++i) {
      const int mt_g = ct * 8 + w + 4 * i;
      const bf16x8 Af = *(const bf16x8*)&WF[(size_t)((mt_g * 4 + ks) * 64 + lane) * 8];
      #pragma unroll
      for (int lt = 0; lt < 4; ++lt)
        acc[i][lt] = __builtin_amdgcn_mfma_f32_16x16x32_bf16(Af, Bf[lt], acc[i][lt], 0, 0, 0);
    }
  }
  if (ct >= 2) {   // z slices: bf16 transpose via LDS -> coalesced ch-major rows
    unsigned short* ht2 = (unsigned short*)xi;   // [128][72] u16
    #pragma unroll
    for (int i = 0; i < 2; ++i) {
      const int lrow = (w + 4 * i) * 16 + (lane >> 4) * 4;  // local z row 0..127
      #pragma unroll
      for (int r = 0; r < 4; ++r)
        #pragma unroll
        for (int lt = 0; lt < 4; ++lt)
          ht2[(lrow + r) * 72 + lt * 16 + colo] = f2bf(acc[i][lt][r]);
    }
    __syncthreads();
    #pragma unroll
    for (int k = 0; k < 4; ++k) {
      const int it = tid + k * 256;      // 1024 items: 128 rows x 8 chunks
      const int row = it >> 3, c8 = it & 7;
      const u16x8 v = *(const u16x8*)&ht2[row * 72 + c8 * 8];
      *(u16x8*)&zH[((size_t)b * kE + (ct - 2) * 128 + row) * kL + l0 + c8 * 8] = v;
    }
    return;
  }
  // xi slices: acc -> LDS
  #pragma unroll
  for (int i = 0; i < 2; ++i) {
    const int mloc = (w + 4 * i) * 16 + (lane >> 4) * 4;
    #pragma unroll
    for (int r = 0; r < 4; ++r)
      #pragma unroll
      for (int lt = 0; lt < 4; ++lt)
        xi[(mloc + r) * 69 + 3 + lt * 16 + colo] = acc[i][lt][r];
  }
  __syncthreads();
  unsigned short* ht = Xs;   // Xs dead after MFMA loop; 64*72 u16 fits
  const int e = tid >> 2, q = tid & 3;
  #pragma unroll
  for (int half = 0; half < 2; ++half) {
    const int ee = e + 64 * half;
    const int ge = ct * 128 + ee;
    const float4 cw = ((const float4*)conv_w)[ge];
    const float cb = conv_b[ge];
    const float* xr = &xi[ee * 69 + q * 16];
    float o[16];
    #pragma unroll
    for (int j = 0; j < 16; ++j) {
      const float s = cb + cw.x * xr[j] + cw.y * xr[j + 1] + cw.z * xr[j + 2] + cw.w * xr[j + 3];
      o[j] = silu(s);
    }
    u16x8 h0, h1;
    #pragma unroll
    for (int i = 0; i < 8; ++i) { h0[i] = f2bf(o[i]); h1[i] = f2bf(o[8 + i]); }
    // channel-major bf16 xc (coalesced 16B per thread)
    unsigned short* crow = &xcC[((size_t)b * kE + ge) * kL + l0 + q * 16];
    *(u16x8*)crow = h0;
    *(u16x8*)(crow + 8) = h1;
    if (half) __syncthreads();    // previous transpose reads done before overwrite
    *(u16x8*)&ht[e * 72 + q * 16]     = h0;
    *(u16x8*)&ht[e * 72 + q * 16 + 8] = h1;
    __syncthreads();
    const int lr = tid >> 2, g = tid & 3;
    u16x8 r0, r1;
    #pragma unroll
    for (int i = 0; i < 8; ++i) {
      r0[i] = ht[(g * 16 + i) * 72 + lr];
      r1[i] = ht[(g * 16 + 8 + i) * 72 + lr];
    }
    unsigned short* orow = &xcH[((size_t)b * kL + l0 + lr) * kE + ct * 128 + half * 64 + g * 16];
    *(u16x8*)orow = r0;
    *(u16x8*)(orow + 8) = r1;
  }
}

// ---------------------------------------------------------------------------
// Kernel: dbc GEMM (M=288, K=256, CT=2). dt rows -> softplus -> dtT fp32.
// bc rows (ct==1) -> LDS -> interleaved bcQ bf16 [b][8][L][{B2p,C2p,B2p+1,C2p+1}]
// ---------------------------------------------------------------------------
__global__ __launch_bounds__(256) void k_dbc(const unsigned short* __restrict__ XH,
                                             const unsigned short* __restrict__ WF,
                                             const float* __restrict__ bdt,
                                             float* __restrict__ dtT,
                                             unsigned short* __restrict__ bcQ) {
  constexpr int KPAD = 264;
  __shared__ unsigned short Xs[64 * KPAD];
  __shared__ float bcTile[32 * 68];
  const int b = blockIdx.z, ct = blockIdx.y, l0 = blockIdx.x * 64;
  const int tid = threadIdx.x, lane = tid & 63, w = tid >> 6;
  for (int si = tid; si < 64 * 32; si += 256) {
    const int l = si >> 5, k8 = si & 31;
    *(uint4*)&Xs[l * KPAD + k8 * 8] =
        *(const uint4*)&XH[((size_t)(b * kL + l0 + l)) * kE + k8 * 8];
  }
  __syncthreads();
  f32x4 acc[3][4];
  #pragma unroll
  for (int i = 0; i < 3; ++i)
    #pragma unroll
    for (int lt = 0; lt < 4; ++lt) acc[i][lt] = (f32x4){0.f, 0.f, 0.f, 0.f};
  const int colo = lane & 15, kgrp = (lane >> 4) * 8;
  for (int ks = 0; ks < 8; ++ks) {
    bf16x8 Bf[4];
    #pragma unroll
    for (int lt = 0; lt < 4; ++lt)
      Bf[lt] = *(const bf16x8*)&Xs[(lt * 16 + colo) * KPAD + ks * 32 + kgrp];
    #pragma unroll
    for (int i = 0; i < 3; ++i) {
      const int mt = w + 4 * i;
      if (mt < 9) {
        const int mt_g = ct * 9 + mt;
        const bf16x8 Af = *(const bf16x8*)&WF[(size_t)((mt_g * 8 + ks) * 64 + lane) * 8];
        #pragma unroll
        for (int lt = 0; lt < 4; ++lt)
          acc[i][lt] = __builtin_amdgcn_mfma_f32_16x16x32_bf16(Af, Bf[lt], acc[i][lt], 0, 0, 0);
      }
    }
  }
  #pragma unroll
  for (int i = 0; i < 3; ++i) {
    const int mt = w + 4 * i;
    if (mt >= 9) continue;
    const int mbase = (ct * 9 + mt) * 16 + (lane >> 4) * 4;
    #pragma unroll
    for (int r = 0; r < 4; ++r) {
      const int m = mbase + r;
      #pragma unroll
      for (int lt = 0; lt < 4; ++lt) {
        const int ll = lt * 16 + colo;
        const float v = acc[i][lt][r];
        if (m < 256) dtT[((size_t)b * kE + m) * kL + l0 + ll] = softplusf(v + bdt[m]);
        else         bcTile[(m - 256) * 68 + ll] = v;
      }
    }
  }
  if (ct == 1) {
    __syncthreads();
    #pragma unroll
    for (int k = 0; k < 2; ++k) {
      const int it = tid + k * 256;        // 512 items: p 0..7 x l 0..63
      const int p = it >> 6, l = it & 63;
      ushort4 ov;
      ov.x = f2bf(bcTile[(2 * p) * 68 + l]);
      ov.y = f2bf(bcTile[(16 + 2 * p) * 68 + l]);
      ov.z = f2bf(bcTile[(2 * p + 1) * 68 + l]);
      ov.w = f2bf(bcTile[(17 + 2 * p) * 68 + l]);
      *(ushort4*)&bcQ[(((size_t)b * 8 + p) * kL + l0 + l) * 4] = ov;
    }
  }
}

// ---------------------------------------------------------------------------
// Kernel: scan phase A — LDS-free, broadcast global streams.
// thread (ds 0..31, ng 0..7); dt fp32 + xc bf16 + bcQ bf16.
// ---------------------------------------------------------------------------
__global__ __launch_bounds__(256) void k_scanA(const float* __restrict__ dtT,
                                               const unsigned short* __restrict__ xcC,
                                               const unsigned short* __restrict__ bcQ,
                                               const float* __restrict__ A_log,
                                               float* __restrict__ hloc,
                                               float* __restrict__ aprod) {
  const int b = blockIdx.z, ch = blockIdx.x, d0 = blockIdx.y * 32;
  const int l0 = ch * kCL, tid = threadIdx.x;
  const int ds = tid >> 3, ng = tid & 7;
  const int d = d0 + ds;
  const float2 Al = *(const float2*)&A_log[d * kN + 2 * ng];
  const float Av0 = -__expf(Al.x), Av1 = -__expf(Al.y);
  const float4* dt4 = (const float4*)&dtT[((size_t)b * kE + d) * kL + l0];
  const ushort4* xc4 = (const ushort4*)&xcC[((size_t)b * kE + d) * kL + l0];
  const u16x8* bc8 = (const u16x8*)&bcQ[(((size_t)b * 8 + ng) * kL + l0) * 4];
  float h0 = 0.f, h1 = 0.f, sdt = 0.f;
  #pragma unroll 4
  for (int lq = 0; lq < 16; ++lq) {
    const float4 dtv = dt4[lq];
    const ushort4 xcv = xc4[lq];
    const u16x8 bcA = bc8[2 * lq], bcB = bc8[2 * lq + 1];
    float dtj, u;
    dtj = dtv.x; u = dtj * bf2f(xcv.x); sdt += dtj;
    h0 = fmaf(__expf(Av0 * dtj), h0, bf2f(bcA[0]) * u);
    h1 = fmaf(__expf(Av1 * dtj), h1, bf2f(bcA[2]) * u);
    dtj = dtv.y; u = dtj * bf2f(xcv.y); sdt += dtj;
    h0 = fmaf(__expf(Av0 * dtj), h0, bf2f(bcA[4]) * u);
    h1 = fmaf(__expf(Av1 * dtj), h1, bf2f(bcA[6]) * u);
    dtj = dtv.z; u = dtj * bf2f(xcv.z); sdt += dtj;
    h0 = fmaf(__expf(Av0 * dtj), h0, bf2f(bcB[0]) * u);
    h1 = fmaf(__expf(Av1 * dtj), h1, bf2f(bcB[2]) * u);
    dtj = dtv.w; u = dtj * bf2f(xcv.w); sdt += dtj;
    h0 = fmaf(__expf(Av0 * dtj), h0, bf2f(bcB[4]) * u);
    h1 = fmaf(__expf(Av1 * dtj), h1, bf2f(bcB[6]) * u);
  }
  const size_t base = (((size_t)b * kNC + ch) * kE + d) * kN + 2 * ng;
  *(float2*)&hloc[base] = make_float2(h0, h1);
  *(float2*)&aprod[base] = make_float2(__expf(Av0 * sdt), __expf(Av1 * sdt));
}

// ---------------------------------------------------------------------------
// Kernel: prefix over chunks, 8 segment-threads per (b,d,n) row. In-place.
// ---------------------------------------------------------------------------
__global__ __launch_bounds__(256) void k_prefix8(float* __restrict__ hs,
                                                 const float* __restrict__ aprod) {
  const int t = blockIdx.x * 256 + threadIdx.x;
  const int row = t >> 3, seg = t & 7;           // row = b*4096 + dn
  const int b = row >> 12, dn = row & 4095;
  const size_t idx0 = ((size_t)b * kNC + seg * 16) * 4096 + dn;
  float hl[16], ap[16];
  #pragma unroll
  for (int i = 0; i < 16; ++i) {
    hl[i] = hs[idx0 + (size_t)i * 4096];
    ap[i] = aprod[idx0 + (size_t)i * 4096];
  }
  float H = 0.f, A = 1.f;
  #pragma unroll
  for (int i = 0; i < 16; ++i) { H = fmaf(ap[i], H, hl[i]); A *= ap[i]; }
  #pragma unroll
  for (int off = 1; off < 8; off <<= 1) {
    const float Ho = __shfl_up(H, off, 8);
    const float Ao = __shfl_up(A, off, 8);
    if (seg >= off) { H = fmaf(A, Ho, H); A *= Ao; }
  }
  const float Hprev = __shfl_up(H, 1, 8);
  float h = (seg == 0) ? 0.f : Hprev;
  #pragma unroll
  for (int i = 0; i < 16; ++i) {
    hs[idx0 + (size_t)i * 4096] = h;
    h = fmaf(ap[i], h, hl[i]);
  }
}

// ---------------------------------------------------------------------------
// Kernel: scan phase C — LDS-free loop (broadcast global streams), register-y,
// small yt LDS for transpose, bf16 xc/z gating epilogue.
// ---------------------------------------------------------------------------
__global__ __launch_bounds__(256) void k_scanC(const float* __restrict__ dtT,
                                               const unsigned short* __restrict__ xcC,
                                               const unsigned short* __restrict__ bcQ,
                                               const unsigned short* __restrict__ zH,
                                               const float* __restrict__ A_log,
                                               const float* __restrict__ Dp,
                                               const float* __restrict__ hinit,
                                               unsigned short* __restrict__ yH) {
  __shared__ float yt[32 * 72];
  const int b = blockIdx.z, ch = blockIdx.x, d0 = blockIdx.y * 32;
  const int l0 = ch * kCL, tid = threadIdx.x;
  const int ds = tid >> 3, ng = tid & 7;
  const int d = d0 + ds;
  const float2 Al = *(const float2*)&A_log[d * kN + 2 * ng];
  const float Av0 = -__expf(Al.x), Av1 = -__expf(Al.y);
  const size_t hbase = (((size_t)b * kNC + ch) * kE + d) * kN + 2 * ng;
  const float2 hv = *(const float2*)&hinit[hbase];
  float h0 = hv.x, h1 = hv.y;
  const float4* dt4 = (const float4*)&dtT[((size_t)b * kE + d) * kL + l0];
  const ushort4* xc4 = (const ushort4*)&xcC[((size_t)b * kE + d) * kL + l0];
  const u16x8* bc8 = (const u16x8*)&bcQ[(((size_t)b * 8 + ng) * kL + l0) * 4];
  float yreg[8];
  #pragma unroll
  for (int lq = 0; lq < 16; ++lq) {
    const float4 dtv = dt4[lq];
    const ushort4 xcv = xc4[lq];
    const u16x8 bcA = bc8[2 * lq], bcB = bc8[2 * lq + 1];
    const float dts[4] = {dtv.x, dtv.y, dtv.z, dtv.w};
    const float xcs[4] = {bf2f(xcv.x), bf2f(xcv.y), bf2f(xcv.z), bf2f(xcv.w)};
    #pragma unroll
    for (int j = 0; j < 4; ++j) {
      const int l = 4 * lq + j;
      const u16x8& bb = (j < 2) ? bcA : bcB;
      const int o4 = (j & 1) * 4;
      const float dtj = dts[j], u = dtj * xcs[j];
      h0 = fmaf(__expf(Av0 * dtj), h0, bf2f(bb[o4 + 0]) * u);
      h1 = fmaf(__expf(Av1 * dtj), h1, bf2f(bb[o4 + 2]) * u);
      const float yp = dpp_red8(fmaf(h0, bf2f(bb[o4 + 1]), h1 * bf2f(bb[o4 + 3])));
      if (ng == (l & 7)) yreg[l >> 3] = yp;
    }
  }
  #pragma unroll
  for (int k = 0; k < 8; ++k)
    yt[ds * 72 + 8 * k + ng] = yreg[k];
  __syncthreads();
  const int l = tid >> 2, g = tid & 3;
  u16x8 ov;
  #pragma unroll
  for (int i = 0; i < 8; ++i) {
    const int dd = g * 8 + i;
    const float yv = yt[dd * 72 + l];
    const float xv = bf2f(xcC[((size_t)b * kE + d0 + dd) * kL + l0 + l]);
    const float zv = bf2f(zH[((size_t)b * kE + d0 + dd) * kL + l0 + l]);
    const float o = fmaf(xv, Dp[d0 + dd], yv) * silu(zv);
    ov[i] = f2bf(o);
  }
  *(u16x8*)&yH[((size_t)b * kL + l0 + l) * kE + d0 + g * 8] = ov;
}

// ---------------------------------------------------------------------------
// Kernel: gemm3 (out = W_out @ y), MFMA, unchanged structure.
// ---------------------------------------------------------------------------
__global__ __launch_bounds__(256) void k_gemm3(const unsigned short* __restrict__ XH,
                                               const unsigned short* __restrict__ WF,
                                               float* __restrict__ out) {
  constexpr int KPAD = 264;
  __shared__ unsigned short Xs[64 * KPAD];
  const int b = blockIdx.z, l0 = blockIdx.x * 64;
  const int tid = threadIdx.x, lane = tid & 63, w = tid >> 6;
  for (int si = tid; si < 64 * 32; si += 256) {
    const int l = si >> 5, k8 = si & 31;
    *(uint4*)&Xs[l * KPAD + k8 * 8] =
        *(const uint4*)&XH[((size_t)(b * kL + l0 + l)) * kE + k8 * 8];
  }
  __syncthreads();
  f32x4 acc[2][4];
  #pragma unroll
  for (int i = 0; i < 2; ++i)
    #pragma unroll
    for (int lt = 0; lt < 4; ++lt) acc[i][lt] = (f32x4){0.f, 0.f, 0.f, 0.f};
  const int colo = lane & 15, kgrp = (lane >> 4) * 8;
  for (int ks = 0; ks < 8; ++ks) {
    bf16x8 Bf[4];
    #pragma unroll
    for (int lt = 0; lt < 4; ++lt)
      Bf[lt] = *(const bf16x8*)&Xs[(lt * 16 + colo) * KPAD + ks * 32 + kgrp];
    #pragma unroll
    for (int i = 0; i < 2; ++i) {
      const int mt = w + 4 * i;
      const bf16x8 Af = *(const bf16x8*)&WF[(size_t)((mt * 8 + ks) * 64 + lane) * 8];
      #pragma unroll
      for (int lt = 0; lt < 4; ++lt)
        acc[i][lt] = __builtin_amdgcn_mfma_f32_16x16x32_bf16(Af, Bf[lt], acc[i][lt], 0, 0, 0);
    }
  }
  #pragma unroll
  for (int i = 0; i < 2; ++i) {
    const int mbase = (w + 4 * i) * 16 + (lane >> 4) * 4;
    #pragma unroll
    for (int r = 0; r < 4; ++r)
      #pragma unroll
      for (int lt = 0; lt < 4; ++lt)
        out[((size_t)b * kC + mbase + r) * kL + l0 + lt * 16 + colo] = acc[i][lt][r];
  }
}

// ---------------------------------------------------------------------------
extern "C" void kernel_launch(void* const* d_in, const int* in_sizes, int n_in,
                              void* d_out, int out_size, void* d_ws, size_t ws_size,
                              hipStream_t stream) {
  (void)in_sizes; (void)n_in; (void)out_size; (void)ws_size;
  const float* x      = (const float*)d_in[0];
  const float* ln_w   = (const float*)d_in[1];
  const float* ln_b   = (const float*)d_in[2];
  const float* W_in   = (const float*)d_in[3];
  const float* conv_w = (const float*)d_in[4];
  const float* conv_b = (const float*)d_in[5];
  const float* W_x    = (const float*)d_in[6];
  const float* W_dt   = (const float*)d_in[7];
  const float* b_dt   = (const float*)d_in[8];
  const float* A_log  = (const float*)d_in[9];
  const float* Dp     = (const float*)d_in[10];
  const float* W_out  = (const float*)d_in[11];
  float* out = (float*)d_out;
  float* ws  = (float*)d_ws;

  // workspace layout (float offsets)
  unsigned short* yH  = (unsigned short*)(ws);             // [b][l][256] bf16 (8MB)
  unsigned short* zH  = (unsigned short*)(ws + 4194304);   // [b][e][L] bf16 (8MB)
  unsigned short* xcC = (unsigned short*)(ws + 6291456);   // [b][e][L] bf16 ch-major (8MB)
  unsigned short* xcH = (unsigned short*)(ws + 8388608);   // [b][l][256] bf16 token-major (8MB)
  float* dtT   = ws + 12582912;         // 4,194,304 fp32; alias xnH (dead before dbc)
  unsigned short* bcQ = (unsigned short*)(ws + 16777216);  // [b][8][L][4] bf16 (1MB)
  float* hloc  = ws + 17301504;         // 1,048,576 (in-place -> hinit)
  float* aprod = ws + 18350080;         // 1,048,576
  unsigned short* xnH  = (unsigned short*)(ws + 12582912);
  unsigned short* WinF = (unsigned short*)(ws + 19398656);  //  65,536 u16
  unsigned short* WcatF = WinF + 65536;                     //  73,728 u16
  unsigned short* WoutF = WinF + 139264;                    //  32,768 u16

  k_pre   <<<340, 256, 0, stream>>>(W_in, W_x, W_dt, W_out, WinF, WcatF, WoutF,
                                    x, ln_w, ln_b, xnH);
  k_g1conv<<<dim3(kL / 64, 4, kB), 256, 0, stream>>>(xnH, WinF, W_in, conv_w, conv_b,
                                                     zH, xcC, xcH);
  k_dbc   <<<dim3(kL / 64, 2, kB), 256, 0, stream>>>(xcH, WcatF, b_dt, dtT, bcQ);
  k_scanA <<<dim3(kNC, kE / 32, kB), 256, 0, stream>>>(dtT, xcC, bcQ, A_log, hloc, aprod);
  k_prefix8<<<256, 256, 0, stream>>>(hloc, aprod);
  k_scanC <<<dim3(kNC, kE / 32, kB), 256, 0, stream>>>(dtT, xcC, bcQ, zH, A_log, Dp, hloc, yH);
  k_gemm3 <<<dim3(kL / 64, 1, kB), 256, 0, stream>>>(yH, WoutF, out);
}

// Round 10
// 106.281 us; speedup vs baseline: 1.3723x; 1.3723x over previous
//
#include <hip/hip_runtime.h>

// Problem constants
constexpr int kB  = 2;
constexpr int kL  = 8192;   // d*h*w = 8*32*32
constexpr int kC  = 128;    // D_MODEL
constexpr int kE  = 256;    // D_INNER
constexpr int kN  = 16;     // D_STATE
constexpr int kCL = 64;     // scan chunk length
constexpr int kNC = kL / kCL; // 128 chunks per batch

typedef __attribute__((ext_vector_type(8))) short bf16x8;
typedef __attribute__((ext_vector_type(4))) float f32x4;
typedef __attribute__((ext_vector_type(8))) unsigned short u16x8;

__device__ __forceinline__ float silu(float v) { return v / (1.f + __expf(-v)); }
__device__ __forceinline__ float softplusf(float s) {
  return fmaxf(s, 0.f) + log1pf(__expf(-fabsf(s)));
}
__device__ __forceinline__ unsigned short f2bf(float x) {
  unsigned u = __float_as_uint(x);
  u += 0x7FFF + ((u >> 16) & 1);
  return (unsigned short)(u >> 16);
}
__device__ __forceinline__ float bf2f(unsigned short x) {
  return __uint_as_float(((unsigned)x) << 16);
}
// Sum over aligned 8-lane groups entirely on the VALU pipe (DPP), no DS ops.
__device__ __forceinline__ float dpp_red8(float v) {
  v += __int_as_float(__builtin_amdgcn_mov_dpp(__float_as_int(v), 0xB1, 0xF, 0xF, true));
  v += __int_as_float(__builtin_amdgcn_mov_dpp(__float_as_int(v), 0x4E, 0xF, 0xF, true));
  v += __int_as_float(__builtin_amdgcn_mov_dpp(__float_as_int(v), 0x141, 0xF, 0xF, true));
  return v;
}

// ---------------------------------------------------------------------------
// Kernel: fused weight-prep (blocks 0..83) + LayerNorm (blocks 84..339).
// ---------------------------------------------------------------------------
__global__ __launch_bounds__(256) void k_pre(const float* __restrict__ W_in,
                                             const float* __restrict__ W_x,
                                             const float* __restrict__ W_dt,
                                             const float* __restrict__ W_out,
                                             unsigned short* __restrict__ WinF,
                                             unsigned short* __restrict__ WcatF,
                                             unsigned short* __restrict__ WoutF,
                                             const float* __restrict__ x,
                                             const float* __restrict__ ln_w,
                                             const float* __restrict__ ln_b,
                                             unsigned short* __restrict__ xnH) {
  const int tid = threadIdx.x;
  if (blockIdx.x < 84) {
    const int f = blockIdx.x * 256 + tid;
    u16x8 o;
    if (f < 8192) {
      const int lane = f & 63, ks = (f >> 6) & 3, mt = f >> 8;
      const int m = mt * 16 + (lane & 15), kb = ks * 32 + ((lane >> 4) << 3);
      #pragma unroll
      for (int j = 0; j < 8; ++j) o[j] = f2bf(W_in[m * 128 + kb + j]);
      *(u16x8*)&WinF[(size_t)f * 8] = o;
    } else if (f < 17408) {
      const int g = f - 8192;
      const int lane = g & 63, ks = (g >> 6) & 7, mt = g >> 9;
      const int m = mt * 16 + (lane & 15), kb = ks * 32 + ((lane >> 4) << 3);
      if (m < 256) {
        #pragma unroll
        for (int j = 0; j < 8; ++j) {
          float s = 0.f;
          #pragma unroll
          for (int r = 0; r < 8; ++r) s = fmaf(W_dt[m * 8 + r], W_x[r * 256 + kb + j], s);
          o[j] = f2bf(s);
        }
      } else {
        #pragma unroll
        for (int j = 0; j < 8; ++j) o[j] = f2bf(W_x[(8 + m - 256) * 256 + kb + j]);
      }
      *(u16x8*)&WcatF[(size_t)g * 8] = o;
    } else {
      const int g = f - 17408;
      const int lane = g & 63, ks = (g >> 6) & 7, mt = g >> 9;
      const int m = mt * 16 + (lane & 15), kb = ks * 32 + ((lane >> 4) << 3);
      #pragma unroll
      for (int j = 0; j < 8; ++j) o[j] = f2bf(W_out[m * 256 + kb + j]);
      *(u16x8*)&WoutF[(size_t)g * 8] = o;
    }
    return;
  }
  // ---- LayerNorm part ----
  __shared__ float tile[64 * 132];
  __shared__ float smu[64], srs[64];
  const int bx2 = blockIdx.x - 84;
  const int b = bx2 >> 7, l0 = (bx2 & 127) * 64;
  const int cc = tid >> 6, lt = tid & 63;
  const float* xb = x + (size_t)b * kC * kL;
  for (int c0 = 0; c0 < kC; c0 += 4)
    tile[lt * 132 + c0 + cc] = xb[(size_t)(c0 + cc) * kL + l0 + lt];
  __syncthreads();
  const int l = tid >> 2, q = tid & 3;
  float s = 0.f, s2 = 0.f;
  #pragma unroll
  for (int i = 0; i < 32; ++i) {
    const float v = tile[l * 132 + q + 4 * i];
    s += v; s2 += v * v;
  }
  s += __shfl_xor(s, 1);  s2 += __shfl_xor(s2, 1);
  s += __shfl_xor(s, 2);  s2 += __shfl_xor(s2, 2);
  if (q == 0) {
    const float mu = s * (1.f / 128.f);
    const float var = s2 * (1.f / 128.f) - mu * mu;
    smu[l] = mu; srs[l] = rsqrtf(var + 1e-5f);
  }
  __syncthreads();
  #pragma unroll
  for (int it = 0; it < 4; ++it) {
    const int fidx = tid + it * 256;
    const int li = fidx >> 4, c8 = fidx & 15;
    const float4 v0 = *(const float4*)&tile[li * 132 + c8 * 8];
    const float4 v1 = *(const float4*)&tile[li * 132 + c8 * 8 + 4];
    const float4 w0 = *(const float4*)&ln_w[c8 * 8];
    const float4 w1 = *(const float4*)&ln_w[c8 * 8 + 4];
    const float4 b0 = *(const float4*)&ln_b[c8 * 8];
    const float4 b1 = *(const float4*)&ln_b[c8 * 8 + 4];
    const float mu = smu[li], rs = srs[li];
    u16x8 o;
    o[0] = f2bf((v0.x - mu) * rs * w0.x + b0.x);
    o[1] = f2bf((v0.y - mu) * rs * w0.y + b0.y);
    o[2] = f2bf((v0.z - mu) * rs * w0.z + b0.z);
    o[3] = f2bf((v0.w - mu) * rs * w0.w + b0.w);
    o[4] = f2bf((v1.x - mu) * rs * w1.x + b1.x);
    o[5] = f2bf((v1.y - mu) * rs * w1.y + b1.y);
    o[6] = f2bf((v1.z - mu) * rs * w1.z + b1.z);
    o[7] = f2bf((v1.w - mu) * rs * w1.w + b1.w);
    *(u16x8*)&xnH[((size_t)b * kL + l0 + li) * kC + c8 * 8] = o;
  }
}

// ---------------------------------------------------------------------------
// Kernel: fused GEMM1 + depthwise conv + silu.
// ct 0..1: xi slices -> conv -> xcC bf16 ch-major + xcH bf16 token-major
// ct 2..3: z slices  -> LDS transpose -> zH bf16 ch-major (coalesced)
// ---------------------------------------------------------------------------
__global__ __launch_bounds__(256) void k_g1conv(const unsigned short* __restrict__ xnH,
                                                const unsigned short* __restrict__ WF,
                                                const float* __restrict__ W_in,
                                                const float* __restrict__ conv_w,
                                                const float* __restrict__ conv_b,
                                                unsigned short* __restrict__ zH,
                                                unsigned short* __restrict__ xcC,
                                                unsigned short* __restrict__ xcH) {
  constexpr int KPAD = 136;
  __shared__ unsigned short Xs[64 * KPAD];   // staging; aliased as ht[64*72] later
  __shared__ float xi[128 * 69];             // conv tile; aliased as ht2 u16[128*72] (z path)
  const int b = blockIdx.z, ct = blockIdx.y, l0 = blockIdx.x * 64;
  const int tid = threadIdx.x, lane = tid & 63, w = tid >> 6;
  for (int si = tid; si < 1024; si += 256) {
    const int l = si >> 4, k8 = si & 15;
    *(uint4*)&Xs[l * KPAD + k8 * 8] =
        *(const uint4*)&xnH[((size_t)(b * kL + l0 + l)) * kC + k8 * 8];
  }
  __syncthreads();
  // boundary-token xi via VALU (xi slices only); zeros when l0 == 0
  float s0 = 0.f, s1 = 0.f, s2 = 0.f;
  if (ct < 2 && tid < 128 && l0 > 0) {
    const int ge = ct * 128 + tid;
    const float4* wv = (const float4*)&W_in[ge * kC];
    const u16x8* x0 = (const u16x8*)&xnH[((size_t)b * kL + l0 - 3) * kC];
    const u16x8* x1 = (const u16x8*)&xnH[((size_t)b * kL + l0 - 2) * kC];
    const u16x8* x2 = (const u16x8*)&xnH[((size_t)b * kL + l0 - 1) * kC];
    #pragma unroll 4
    for (int k8 = 0; k8 < 16; ++k8) {
      const float4 wa = wv[2 * k8], wb = wv[2 * k8 + 1];
      const u16x8 a0 = x0[k8], a1 = x1[k8], a2 = x2[k8];
      const float wreg[8] = {wa.x, wa.y, wa.z, wa.w, wb.x, wb.y, wb.z, wb.w};
      #pragma unroll
      for (int j = 0; j < 8; ++j) {
        s0 = fmaf(wreg[j], bf2f(a0[j]), s0);
        s1 = fmaf(wreg[j], bf2f(a1[j]), s1);
        s2 = fmaf(wreg[j], bf2f(a2[j]), s2);
      }
    }
  }
  if (ct < 2 && tid < 128) {
    xi[tid * 69 + 0] = s0; xi[tid * 69 + 1] = s1; xi[tid * 69 + 2] = s2;
  }
  // MFMA: 128 rows of this ct-slice; waves do mt = w, w+4
  f32x4 acc[2][4];
  #pragma unroll
  for (int i = 0; i < 2; ++i)
    #pragma unroll
    for (int lt = 0; lt < 4; ++lt) acc[i][lt] = (f32x4){0.f, 0.f, 0.f, 0.f};
  const int colo = lane & 15, kgrp = (lane >> 4) * 8;
  for (int ks = 0; ks < 4; ++ks) {
    bf16x8 Bf[4];
    #pragma unroll
    for (int lt = 0; lt < 4; ++lt)
      Bf[lt] = *(const bf16x8*)&Xs[(lt * 16 + colo) * KPAD + ks * 32 + kgrp];
    #pragma unroll
    for (int i = 0; i < 2; ++i) {
      const int mt_g = ct * 8 + w + 4 * i;
      const bf16x8 Af = *(const bf16x8*)&WF[(size_t)((mt_g * 4 + ks) * 64 + lane) * 8];
      #pragma unroll
      for (int lt = 0; lt < 4; ++lt)
        acc[i][lt] = __builtin_amdgcn_mfma_f32_16x16x32_bf16(Af, Bf[lt], acc[i][lt], 0, 0, 0);
    }
  }
  if (ct >= 2) {   // z slices: bf16 transpose via LDS -> coalesced ch-major rows
    unsigned short* ht2 = (unsigned short*)xi;   // [128][72] u16
    #pragma unroll
    for (int i = 0; i < 2; ++i) {
      const int lrow = (w + 4 * i) * 16 + (lane >> 4) * 4;  // local z row 0..127
      #pragma unroll
      for (int r = 0; r < 4; ++r)
        #pragma unroll
        for (int lt = 0; lt < 4; ++lt)
          ht2[(lrow + r) * 72 + lt * 16 + colo] = f2bf(acc[i][lt][r]);
    }
    __syncthreads();
    #pragma unroll
    for (int k = 0; k < 4; ++k) {
      const int it = tid + k * 256;      // 1024 items: 128 rows x 8 chunks
      const int row = it >> 3, c8 = it & 7;
      const u16x8 v = *(const u16x8*)&ht2[row * 72 + c8 * 8];
      *(u16x8*)&zH[((size_t)b * kE + (ct - 2) * 128 + row) * kL + l0 + c8 * 8] = v;
    }
    return;
  }
  // xi slices: acc -> LDS
  #pragma unroll
  for (int i = 0; i < 2; ++i) {
    const int mloc = (w + 4 * i) * 16 + (lane >> 4) * 4;
    #pragma unroll
    for (int r = 0; r < 4; ++r)
      #pragma unroll
      for (int lt = 0; lt < 4; ++lt)
        xi[(mloc + r) * 69 + 3 + lt * 16 + colo] = acc[i][lt][r];
  }
  __syncthreads();
  unsigned short* ht = Xs;   // Xs dead after MFMA loop; 64*72 u16 fits
  const int e = tid >> 2, q = tid & 3;
  #pragma unroll
  for (int half = 0; half < 2; ++half) {
    const int ee = e + 64 * half;
    const int ge = ct * 128 + ee;
    const float4 cw = ((const float4*)conv_w)[ge];
    const float cb = conv_b[ge];
    const float* xr = &xi[ee * 69 + q * 16];
    float o[16];
    #pragma unroll
    for (int j = 0; j < 16; ++j) {
      const float s = cb + cw.x * xr[j] + cw.y * xr[j + 1] + cw.z * xr[j + 2] + cw.w * xr[j + 3];
      o[j] = silu(s);
    }
    u16x8 h0, h1;
    #pragma unroll
    for (int i = 0; i < 8; ++i) { h0[i] = f2bf(o[i]); h1[i] = f2bf(o[8 + i]); }
    // channel-major bf16 xc (coalesced 16B per thread)
    unsigned short* crow = &xcC[((size_t)b * kE + ge) * kL + l0 + q * 16];
    *(u16x8*)crow = h0;
    *(u16x8*)(crow + 8) = h1;
    if (half) __syncthreads();    // previous transpose reads done before overwrite
    *(u16x8*)&ht[e * 72 + q * 16]     = h0;
    *(u16x8*)&ht[e * 72 + q * 16 + 8] = h1;
    __syncthreads();
    const int lr = tid >> 2, g = tid & 3;
    u16x8 r0, r1;
    #pragma unroll
    for (int i = 0; i < 8; ++i) {
      r0[i] = ht[(g * 16 + i) * 72 + lr];
      r1[i] = ht[(g * 16 + 8 + i) * 72 + lr];
    }
    unsigned short* orow = &xcH[((size_t)b * kL + l0 + lr) * kE + ct * 128 + half * 64 + g * 16];
    *(u16x8*)orow = r0;
    *(u16x8*)(orow + 8) = r1;
  }
}

// ---------------------------------------------------------------------------
// Kernel: dbc GEMM (M=288, K=256, CT=2). dt rows -> softplus -> dtT fp32.
// bc rows (ct==1) -> LDS -> interleaved bcQ bf16 [b][8][L][{B2p,C2p,B2p+1,C2p+1}]
// ---------------------------------------------------------------------------
__global__ __launch_bounds__(256) void k_dbc(const unsigned short* __restrict__ XH,
                                             const unsigned short* __restrict__ WF,
                                             const float* __restrict__ bdt,
                                             float* __restrict__ dtT,
                                             unsigned short* __restrict__ bcQ) {
  constexpr int KPAD = 264;
  __shared__ unsigned short Xs[64 * KPAD];
  __shared__ float bcTile[32 * 68];
  const int b = blockIdx.z, ct = blockIdx.y, l0 = blockIdx.x * 64;
  const int tid = threadIdx.x, lane = tid & 63, w = tid >> 6;
  for (int si = tid; si < 64 * 32; si += 256) {
    const int l = si >> 5, k8 = si & 31;
    *(uint4*)&Xs[l * KPAD + k8 * 8] =
        *(const uint4*)&XH[((size_t)(b * kL + l0 + l)) * kE + k8 * 8];
  }
  __syncthreads();
  f32x4 acc[3][4];
  #pragma unroll
  for (int i = 0; i < 3; ++i)
    #pragma unroll
    for (int lt = 0; lt < 4; ++lt) acc[i][lt] = (f32x4){0.f, 0.f, 0.f, 0.f};
  const int colo = lane & 15, kgrp = (lane >> 4) * 8;
  for (int ks = 0; ks < 8; ++ks) {
    bf16x8 Bf[4];
    #pragma unroll
    for (int lt = 0; lt < 4; ++lt)
      Bf[lt] = *(const bf16x8*)&Xs[(lt * 16 + colo) * KPAD + ks * 32 + kgrp];
    #pragma unroll
    for (int i = 0; i < 3; ++i) {
      const int mt = w + 4 * i;
      if (mt < 9) {
        const int mt_g = ct * 9 + mt;
        const bf16x8 Af = *(const bf16x8*)&WF[(size_t)((mt_g * 8 + ks) * 64 + lane) * 8];
        #pragma unroll
        for (int lt = 0; lt < 4; ++lt)
          acc[i][lt] = __builtin_amdgcn_mfma_f32_16x16x32_bf16(Af, Bf[lt], acc[i][lt], 0, 0, 0);
      }
    }
  }
  #pragma unroll
  for (int i = 0; i < 3; ++i) {
    const int mt = w + 4 * i;
    if (mt >= 9) continue;
    const int mbase = (ct * 9 + mt) * 16 + (lane >> 4) * 4;
    #pragma unroll
    for (int r = 0; r < 4; ++r) {
      const int m = mbase + r;
      #pragma unroll
      for (int lt = 0; lt < 4; ++lt) {
        const int ll = lt * 16 + colo;
        const float v = acc[i][lt][r];
        if (m < 256) dtT[((size_t)b * kE + m) * kL + l0 + ll] = softplusf(v + bdt[m]);
        else         bcTile[(m - 256) * 68 + ll] = v;
      }
    }
  }
  if (ct == 1) {
    __syncthreads();
    #pragma unroll
    for (int k = 0; k < 2; ++k) {
      const int it = tid + k * 256;        // 512 items: p 0..7 x l 0..63
      const int p = it >> 6, l = it & 63;
      ushort4 ov;
      ov.x = f2bf(bcTile[(2 * p) * 68 + l]);
      ov.y = f2bf(bcTile[(16 + 2 * p) * 68 + l]);
      ov.z = f2bf(bcTile[(2 * p + 1) * 68 + l]);
      ov.w = f2bf(bcTile[(17 + 2 * p) * 68 + l]);
      *(ushort4*)&bcQ[(((size_t)b * 8 + p) * kL + l0 + l) * 4] = ov;
    }
  }
}

// ---------------------------------------------------------------------------
// Kernel: scan phase A — LDS-staged (parallel bf16->f32 convert in staging,
// lean serial loop: 2 ds_read_b128 per 2 tokens).
// dxi [ds][l][{dt,u}] stride 132 ; Bp [ng][l][{B2p,B2p+1}] stride 132.
// ---------------------------------------------------------------------------
__global__ __launch_bounds__(256) void k_scanA(const float* __restrict__ dtT,
                                               const unsigned short* __restrict__ xcC,
                                               const unsigned short* __restrict__ bcQ,
                                               const float* __restrict__ A_log,
                                               float* __restrict__ hloc,
                                               float* __restrict__ aprod) {
  __shared__ float dxi[32 * 132];
  __shared__ float Bp[8 * 132];
  const int b = blockIdx.z, ch = blockIdx.x, d0 = blockIdx.y * 32;
  const int l0 = ch * kCL, tid = threadIdx.x;
  const int ds = tid >> 3, ng = tid & 7;
  {
    const float4* dsrc = (const float4*)&dtT[((size_t)b * kE + d0 + ds) * kL + l0 + 8 * ng];
    const u16x8 xv = *(const u16x8*)&xcC[((size_t)b * kE + d0 + ds) * kL + l0 + 8 * ng];
    float* wr = &dxi[ds * 132 + 16 * ng];
    #pragma unroll
    for (int m = 0; m < 2; ++m) {
      const float4 dv = dsrc[m];
      *(float4*)&wr[8 * m]     = make_float4(dv.x, dv.x * bf2f(xv[4 * m + 0]),
                                             dv.y, dv.y * bf2f(xv[4 * m + 1]));
      *(float4*)&wr[8 * m + 4] = make_float4(dv.z, dv.z * bf2f(xv[4 * m + 2]),
                                             dv.w, dv.w * bf2f(xv[4 * m + 3]));
    }
  }
  {
    const int p = tid >> 5, lt2 = tid & 31;    // p-row, token pair
    const u16x8 q = *(const u16x8*)&bcQ[(((size_t)b * 8 + p) * kL + l0 + 2 * lt2) * 4];
    // q = {B2p,C2p,B2p+1,C2p+1}@tok0 ; same @tok1 — keep B's only
    *(float4*)&Bp[p * 132 + 4 * lt2] =
        make_float4(bf2f(q[0]), bf2f(q[2]), bf2f(q[4]), bf2f(q[6]));
  }
  __syncthreads();
  const int d = d0 + ds;
  const float2 Al = *(const float2*)&A_log[d * kN + 2 * ng];
  const float Av0 = -__expf(Al.x), Av1 = -__expf(Al.y);
  float h0 = 0.f, h1 = 0.f, sdt = 0.f;
  const float* drow = &dxi[ds * 132];
  const float* brow = &Bp[ng * 132];
  #pragma unroll 4
  for (int l = 0; l < kCL; l += 2) {
    const float4 du = *(const float4*)&drow[2 * l];   // dt,u @ l ; dt,u @ l+1
    const float4 bb = *(const float4*)&brow[2 * l];   // B0,B1 @ l ; B0,B1 @ l+1
    sdt += du.x + du.z;
    h0 = fmaf(__expf(Av0 * du.x), h0, bb.x * du.y);
    h1 = fmaf(__expf(Av1 * du.x), h1, bb.y * du.y);
    h0 = fmaf(__expf(Av0 * du.z), h0, bb.z * du.w);
    h1 = fmaf(__expf(Av1 * du.z), h1, bb.w * du.w);
  }
  const size_t base = (((size_t)b * kNC + ch) * kE + d) * kN + 2 * ng;
  *(float2*)&hloc[base] = make_float2(h0, h1);
  *(float2*)&aprod[base] = make_float2(__expf(Av0 * sdt), __expf(Av1 * sdt));
}

// ---------------------------------------------------------------------------
// Kernel: prefix over chunks, 8 segment-threads per (b,d,n) row. In-place.
// ---------------------------------------------------------------------------
__global__ __launch_bounds__(256) void k_prefix8(float* __restrict__ hs,
                                                 const float* __restrict__ aprod) {
  const int t = blockIdx.x * 256 + threadIdx.x;
  const int row = t >> 3, seg = t & 7;           // row = b*4096 + dn
  const int b = row >> 12, dn = row & 4095;
  const size_t idx0 = ((size_t)b * kNC + seg * 16) * 4096 + dn;
  float hl[16], ap[16];
  #pragma unroll
  for (int i = 0; i < 16; ++i) {
    hl[i] = hs[idx0 + (size_t)i * 4096];
    ap[i] = aprod[idx0 + (size_t)i * 4096];
  }
  float H = 0.f, A = 1.f;
  #pragma unroll
  for (int i = 0; i < 16; ++i) { H = fmaf(ap[i], H, hl[i]); A *= ap[i]; }
  #pragma unroll
  for (int off = 1; off < 8; off <<= 1) {
    const float Ho = __shfl_up(H, off, 8);
    const float Ao = __shfl_up(A, off, 8);
    if (seg >= off) { H = fmaf(A, Ho, H); A *= Ao; }
  }
  const float Hprev = __shfl_up(H, 1, 8);
  float h = (seg == 0) ? 0.f : Hprev;
  #pragma unroll
  for (int i = 0; i < 16; ++i) {
    hs[idx0 + (size_t)i * 4096] = h;
    h = fmaf(ap[i], h, hl[i]);
  }
}

// ---------------------------------------------------------------------------
// Kernel: scan phase C — LDS-staged, register-y (full unroll),
// yt aliased over dxi (dead after loop), DPP y-reduce on VALU pipe.
// dxi [ds][l][{dt,u}] stride 132 ; bc4 [ng][l][{B0,C0,B1,C1}] stride 260.
// ---------------------------------------------------------------------------
__global__ __launch_bounds__(256) void k_scanC(const float* __restrict__ dtT,
                                               const unsigned short* __restrict__ xcC,
                                               const unsigned short* __restrict__ bcQ,
                                               const unsigned short* __restrict__ zH,
                                               const float* __restrict__ A_log,
                                               const float* __restrict__ Dp,
                                               const float* __restrict__ hinit,
                                               unsigned short* __restrict__ yH) {
  __shared__ float dxi[32 * 132];      // staging; aliased by yt[32*72] post-loop
  __shared__ float bc4[8 * 260];
  float* yt = dxi;
  const int b = blockIdx.z, ch = blockIdx.x, d0 = blockIdx.y * 32;
  const int l0 = ch * kCL, tid = threadIdx.x;
  const int ds = tid >> 3, ng = tid & 7;
  {
    const float4* dsrc = (const float4*)&dtT[((size_t)b * kE + d0 + ds) * kL + l0 + 8 * ng];
    const u16x8 xv = *(const u16x8*)&xcC[((size_t)b * kE + d0 + ds) * kL + l0 + 8 * ng];
    float* wr = &dxi[ds * 132 + 16 * ng];
    #pragma unroll
    for (int m = 0; m < 2; ++m) {
      const float4 dv = dsrc[m];
      *(float4*)&wr[8 * m]     = make_float4(dv.x, dv.x * bf2f(xv[4 * m + 0]),
                                             dv.y, dv.y * bf2f(xv[4 * m + 1]));
      *(float4*)&wr[8 * m + 4] = make_float4(dv.z, dv.z * bf2f(xv[4 * m + 2]),
                                             dv.w, dv.w * bf2f(xv[4 * m + 3]));
    }
  }
  {
    const int p = tid >> 5, lt2 = tid & 31;    // p-row, token pair
    const u16x8 q = *(const u16x8*)&bcQ[(((size_t)b * 8 + p) * kL + l0 + 2 * lt2) * 4];
    float* wr = &bc4[p * 260 + 8 * lt2];
    *(float4*)&wr[0] = make_float4(bf2f(q[0]), bf2f(q[1]), bf2f(q[2]), bf2f(q[3]));
    *(float4*)&wr[4] = make_float4(bf2f(q[4]), bf2f(q[5]), bf2f(q[6]), bf2f(q[7]));
  }
  __syncthreads();
  const int d = d0 + ds;
  const float2 Al = *(const float2*)&A_log[d * kN + 2 * ng];
  const float Av0 = -__expf(Al.x), Av1 = -__expf(Al.y);
  const size_t hbase = (((size_t)b * kNC + ch) * kE + d) * kN + 2 * ng;
  const float2 hv = *(const float2*)&hinit[hbase];
  float h0 = hv.x, h1 = hv.y;
  const float* drow = &dxi[ds * 132];
  const float* brow = &bc4[ng * 260];
  float yreg[8];
  #pragma unroll
  for (int l = 0; l < kCL; l += 2) {
    const float4 du  = *(const float4*)&drow[2 * l];      // dt,u @ l ; dt,u @ l+1
    const float4 bcA = *(const float4*)&brow[4 * l];      // B0,C0,B1,C1 @ l
    const float4 bcB = *(const float4*)&brow[4 * l + 4];  // @ l+1
    h0 = fmaf(__expf(Av0 * du.x), h0, bcA.x * du.y);
    h1 = fmaf(__expf(Av1 * du.x), h1, bcA.z * du.y);
    const float ylo = dpp_red8(fmaf(h0, bcA.y, h1 * bcA.w));
    h0 = fmaf(__expf(Av0 * du.z), h0, bcB.x * du.w);
    h1 = fmaf(__expf(Av1 * du.z), h1, bcB.z * du.w);
    const float yhi = dpp_red8(fmaf(h0, bcB.y, h1 * bcB.w));
    if (ng == (l & 7))       yreg[l >> 3] = ylo;
    if (ng == ((l + 1) & 7)) yreg[l >> 3] = yhi;
  }
  __syncthreads();           // all waves done reading dxi — safe to alias as yt
  #pragma unroll
  for (int k = 0; k < 8; ++k)
    yt[ds * 72 + 8 * k + ng] = yreg[k];
  __syncthreads();
  const int l = tid >> 2, g = tid & 3;
  u16x8 ov;
  #pragma unroll
  for (int i = 0; i < 8; ++i) {
    const int dd = g * 8 + i;
    const float yv = yt[dd * 72 + l];
    const float xv = bf2f(xcC[((size_t)b * kE + d0 + dd) * kL + l0 + l]);
    const float zv = bf2f(zH[((size_t)b * kE + d0 + dd) * kL + l0 + l]);
    const float o = fmaf(xv, Dp[d0 + dd], yv) * silu(zv);
    ov[i] = f2bf(o);
  }
  *(u16x8*)&yH[((size_t)b * kL + l0 + l) * kE + d0 + g * 8] = ov;
}

// ---------------------------------------------------------------------------
// Kernel: gemm3 (out = W_out @ y), MFMA.
// ---------------------------------------------------------------------------
__global__ __launch_bounds__(256) void k_gemm3(const unsigned short* __restrict__ XH,
                                               const unsigned short* __restrict__ WF,
                                               float* __restrict__ out) {
  constexpr int KPAD = 264;
  __shared__ unsigned short Xs[64 * KPAD];
  const int b = blockIdx.z, l0 = blockIdx.x * 64;
  const int tid = threadIdx.x, lane = tid & 63, w = tid >> 6;
  for (int si = tid; si < 64 * 32; si += 256) {
    const int l = si >> 5, k8 = si & 31;
    *(uint4*)&Xs[l * KPAD + k8 * 8] =
        *(const uint4*)&XH[((size_t)(b * kL + l0 + l)) * kE + k8 * 8];
  }
  __syncthreads();
  f32x4 acc[2][4];
  #pragma unroll
  for (int i = 0; i < 2; ++i)
    #pragma unroll
    for (int lt = 0; lt < 4; ++lt) acc[i][lt] = (f32x4){0.f, 0.f, 0.f, 0.f};
  const int colo = lane & 15, kgrp = (lane >> 4) * 8;
  for (int ks = 0; ks < 8; ++ks) {
    bf16x8 Bf[4];
    #pragma unroll
    for (int lt = 0; lt < 4; ++lt)
      Bf[lt] = *(const bf16x8*)&Xs[(lt * 16 + colo) * KPAD + ks * 32 + kgrp];
    #pragma unroll
    for (int i = 0; i < 2; ++i) {
      const int mt = w + 4 * i;
      const bf16x8 Af = *(const bf16x8*)&WF[(size_t)((mt * 8 + ks) * 64 + lane) * 8];
      #pragma unroll
      for (int lt = 0; lt < 4; ++lt)
        acc[i][lt] = __builtin_amdgcn_mfma_f32_16x16x32_bf16(Af, Bf[lt], acc[i][lt], 0, 0, 0);
    }
  }
  #pragma unroll
  for (int i = 0; i < 2; ++i) {
    const int mbase = (w + 4 * i) * 16 + (lane >> 4) * 4;
    #pragma unroll
    for (int r = 0; r < 4; ++r)
      #pragma unroll
      for (int lt = 0; lt < 4; ++lt)
        out[((size_t)b * kC + mbase + r) * kL + l0 + lt * 16 + colo] = acc[i][lt][r];
  }
}

// ---------------------------------------------------------------------------
extern "C" void kernel_launch(void* const* d_in, const int* in_sizes, int n_in,
                              void* d_out, int out_size, void* d_ws, size_t ws_size,
                              hipStream_t stream) {
  (void)in_sizes; (void)n_in; (void)out_size; (void)ws_size;
  const float* x      = (const float*)d_in[0];
  const float* ln_w   = (const float*)d_in[1];
  const float* ln_b   = (const float*)d_in[2];
  const float* W_in   = (const float*)d_in[3];
  const float* conv_w = (const float*)d_in[4];
  const float* conv_b = (const float*)d_in[5];
  const float* W_x    = (const float*)d_in[6];
  const float* W_dt   = (const float*)d_in[7];
  const float* b_dt   = (const float*)d_in[8];
  const float* A_log  = (const float*)d_in[9];
  const float* Dp     = (const float*)d_in[10];
  const float* W_out  = (const float*)d_in[11];
  float* out = (float*)d_out;
  float* ws  = (float*)d_ws;

  // workspace layout (float offsets)
  unsigned short* yH  = (unsigned short*)(ws);             // [b][l][256] bf16 (8MB)
  unsigned short* zH  = (unsigned short*)(ws + 4194304);   // [b][e][L] bf16 (8MB)
  unsigned short* xcC = (unsigned short*)(ws + 6291456);   // [b][e][L] bf16 ch-major (8MB)
  unsigned short* xcH = (unsigned short*)(ws + 8388608);   // [b][l][256] bf16 token-major (8MB)
  float* dtT   = ws + 12582912;         // 4,194,304 fp32; alias xnH (dead before dbc)
  unsigned short* bcQ = (unsigned short*)(ws + 16777216);  // [b][8][L][4] bf16 (1MB)
  float* hloc  = ws + 17301504;         // 1,048,576 (in-place -> hinit)
  float* aprod = ws + 18350080;         // 1,048,576
  unsigned short* xnH  = (unsigned short*)(ws + 12582912);
  unsigned short* WinF = (unsigned short*)(ws + 19398656);  //  65,536 u16
  unsigned short* WcatF = WinF + 65536;                     //  73,728 u16
  unsigned short* WoutF = WinF + 139264;                    //  32,768 u16

  k_pre   <<<340, 256, 0, stream>>>(W_in, W_x, W_dt, W_out, WinF, WcatF, WoutF,
                                    x, ln_w, ln_b, xnH);
  k_g1conv<<<dim3(kL / 64, 4, kB), 256, 0, stream>>>(xnH, WinF, W_in, conv_w, conv_b,
                                                     zH, xcC, xcH);
  k_dbc   <<<dim3(kL / 64, 2, kB), 256, 0, stream>>>(xcH, WcatF, b_dt, dtT, bcQ);
  k_scanA <<<dim3(kNC, kE / 32, kB), 256, 0, stream>>>(dtT, xcC, bcQ, A_log, hloc, aprod);
  k_prefix8<<<256, 256, 0, stream>>>(hloc, aprod);
  k_scanC <<<dim3(kNC, kE / 32, kB), 256, 0, stream>>>(dtT, xcC, bcQ, zH, A_log, Dp, hloc, yH);
  k_gemm3 <<<dim3(kL / 64, 1, kB), 256, 0, stream>>>(yH, WoutF, out);
}